// Round 4
// baseline (937.306 us; speedup 1.0000x reference)
//
#include <hip/hip_runtime.h>
#include <hip/hip_bf16.h>
#include <cstdio>
#include <cstdint>

typedef __bf16 bf16x8 __attribute__((ext_vector_type(8)));
typedef unsigned short u16;
typedef u16 u16x8 __attribute__((ext_vector_type(8)));
typedef float f32x4 __attribute__((ext_vector_type(4)));

#define DEV __device__ __forceinline__

static constexpr int B_ = 8, S_ = 2048, E_ = 768, NQ_ = 128, FF_ = 3072;
static constexpr int BS_ = B_ * S_;

DEV u16 f2b(float f) {
    unsigned u = __builtin_bit_cast(unsigned, f);
    unsigned r = (u + 0x7fffu + ((u >> 16) & 1u)) >> 16;
    return (u16)r;
}

DEV f32x4 mfma16(bf16x8 a, bf16x8 b, f32x4 c) {
    return __builtin_amdgcn_mfma_f32_16x16x32_bf16(a, b, c, 0, 0, 0);
}

#define GLD16(gp, lp) __builtin_amdgcn_global_load_lds( \
    (const __attribute__((address_space(1))) void*)(gp), \
    (__attribute__((address_space(3))) void*)(lp), 16, 0, 0)

// ---------------------------------------------------------------------------
// f32 -> bf16 convert (vectorized float4 -> ushort4)
// ---------------------------------------------------------------------------
__global__ void cvt_bf16(const float* __restrict__ in, u16* __restrict__ out, int n)
{
    const int stride = gridDim.x * blockDim.x * 4;
    for (int i = (blockIdx.x * blockDim.x + threadIdx.x) * 4; i < n; i += stride) {
        const float4 f = *(const float4*)(in + i);
        ushort4 u;
        u.x = f2b(f.x); u.y = f2b(f.y); u.z = f2b(f.z); u.w = f2b(f.w);
        *(ushort4*)(out + i) = u;
    }
}

// ---------------------------------------------------------------------------
// Templated (optionally batched) GEMM: C[M,N] = A[M,K] * B[N,K]^T
// 128x128 tile, BK=64, 4 waves (2x2 of 64x64), global_load_lds staging with
// XOR-swizzled LDS (inverse swizzle applied to the global source address).
//
// XCD-aware chunked block swizzle (bijective; total blocks % 8 == 0 here).
// SWAP=true swaps the x/y tile axes (grid launched (ntiles, mtiles)).
//
// Epilogue: LDS-bounce (As/Bs dead after K-loop) so every global store is a
// full 128B-line coalesced segment; f32 streaming outputs use non-temporal
// stores (read exactly once downstream) to avoid write-allocate/RFO and to
// keep the L2 free for operand panels.  (Round-3 counters: scores GEMM wrote
// 880 MB vs 134 MB unique -> 6.5x write amplification from 64B/32B partial-
// line scattered stores.)
//
// MODE 0: out bf16 = cos(c + bias[col])       (qa)      cached stores
// MODE 1: out bf16 = relu(c + bias[col])      (h)       cached stores
// MODE 2: out f32  = c + bias[col]            (ffn)     NT stores
// MODE 3: out f32  = c                        (attn@qa) NT stores
// MODE 4: out f32  = c * (1/sqrt(8))          (scores)  NT stores
// ---------------------------------------------------------------------------
template<int K, int MODE, bool SWAP = false>
__global__ __launch_bounds__(256)
void gemm_bt(const u16* __restrict__ A, const u16* __restrict__ Bm,
             const float* __restrict__ bias, void* __restrict__ out, int N,
             size_t sA, size_t sB, size_t sC)
{
    __shared__ __align__(16) char smem[32768];
    u16* As = (u16*)smem;              // 128x64 u16 = 16 KB
    u16* Bs = As + 128 * 64;           // 128x64 u16 = 16 KB
    float* smf = (float*)smem;         // epilogue bounce: 32 x stride132 f32
    u16*   smu = (u16*)smem;           // epilogue bounce: 32 x stride136 u16

    const int t = threadIdx.x;
    const int w = t >> 6, lane = t & 63;

    // XCD-aware chunked swizzle (pure bijective remap of block roles)
    const int gx = gridDim.x, gy = gridDim.y;
    const int chunk = (gx * gy * gridDim.z) >> 3;
    const int lid = blockIdx.x + gx * (blockIdx.y + gy * blockIdx.z);
    const int role = (lid & 7) * chunk + (lid >> 3);
    const int xt = role % gx;
    const int yt = (role / gx) % gy;
    const int bz = role / (gx * gy);
    const int m0 = (SWAP ? yt : xt) * 128;
    const int n0 = (SWAP ? xt : yt) * 128;

    const int wr = w >> 1, wc = w & 1;
    A  += (size_t)bz * sA;
    Bm += (size_t)bz * sB;
    u16*   ob16 = (u16*)out   + (size_t)bz * sC;
    float* of32 = (float*)out + (size_t)bz * sC;
    f32x4 acc[4][4] = {};

    for (int k0 = 0; k0 < K; k0 += 64) {
        __syncthreads();
        #pragma unroll
        for (int r = 0; r < 4; ++r) {
            const int ci = r * 256 + t;
            const int row = ci >> 3;
            const int colb = ((ci & 7) * 16) ^ ((row & 7) << 4);
            GLD16(A  + (size_t)(m0 + row) * K + k0 + (colb >> 1),
                  As + (size_t)(r * 256 + w * 64) * 8);
            GLD16(Bm + (size_t)(n0 + row) * K + k0 + (colb >> 1),
                  Bs + (size_t)(r * 256 + w * 64) * 8);
        }
        __syncthreads();
        #pragma unroll
        for (int kk = 0; kk < 2; ++kk) {
            bf16x8 af[4], bf[4];
            const int cb = kk * 64 + ((lane >> 4) << 4);  // byte offset in row
            #pragma unroll
            for (int m = 0; m < 4; ++m) {
                const int row = wr * 64 + m * 16 + (lane & 15);
                af[m] = *(const bf16x8*)((const char*)As + row * 128 + (cb ^ ((row & 7) << 4)));
            }
            #pragma unroll
            for (int n = 0; n < 4; ++n) {
                const int row = wc * 64 + n * 16 + (lane & 15);
                bf[n] = *(const bf16x8*)((const char*)Bs + row * 128 + (cb ^ ((row & 7) << 4)));
            }
            #pragma unroll
            for (int m = 0; m < 4; ++m)
                #pragma unroll
                for (int n = 0; n < 4; ++n)
                    acc[m][n] = mfma16(af[m], bf[n], acc[m][n]);
        }
    }

    // ---- LDS-bounce epilogue: C/D frag layout col=lane&15, row=(lane>>4)*4+r
    constexpr bool F32OUT = (MODE >= 2);
    __syncthreads();                        // K-loop LDS reads complete
    #pragma unroll
    for (int m = 0; m < 4; ++m) {
        // write phase: each wave deposits its quadrant of the 32x128 slice
        #pragma unroll
        for (int n = 0; n < 4; ++n) {
            const int col = wc * 64 + n * 16 + (lane & 15);   // 0..127 local
            float bv = 0.f;
            if (MODE == 0 || MODE == 1 || MODE == 2) bv = bias[n0 + col];
            #pragma unroll
            for (int r = 0; r < 4; ++r) {
                const int lr = wr * 16 + ((lane >> 4) << 2) + r;  // 0..31
                const float c = acc[m][n][r];
                if (F32OUT) {
                    const float v = (MODE == 2) ? c + bv
                                  : (MODE == 3) ? c
                                  : c * 0.35355339059327373f;
                    smf[lr * 132 + col] = v;
                } else {
                    const u16 v = (MODE == 0) ? f2b(cosf(c + bv))
                                              : f2b(fmaxf(c + bv, 0.f));
                    smu[lr * 136 + col] = v;
                }
            }
        }
        __syncthreads();
        // read+store phase: 256 threads cover 32 rows x 128 cols, full lines
        {
            const int lr = t >> 3, cg = t & 7;
            const int grow = m0 + (lr >> 4) * 64 + m * 16 + (lr & 15);
            if (F32OUT) {
                float* gp = of32 + (size_t)grow * N + n0 + cg * 16;
                const float* sp = smf + lr * 132 + cg * 16;
                #pragma unroll
                for (int j = 0; j < 4; ++j) {
                    const f32x4 v = *(const f32x4*)(sp + j * 4);
                    __builtin_nontemporal_store(v, (f32x4*)(gp + j * 4));
                }
            } else {
                u16* gp = ob16 + (size_t)grow * N + n0 + cg * 16;
                const u16* sp = smu + lr * 136 + cg * 16;
                *(u16x8*)gp = *(const u16x8*)sp;
                *(u16x8*)(gp + 8) = *(const u16x8*)(sp + 8);
            }
        }
        __syncthreads();
    }
}

// ---------------------------------------------------------------------------
// Tiled bf16 transpose: in [B][S][E] -> out [B][E][S], 64x64 tiles.
// ---------------------------------------------------------------------------
__global__ __launch_bounds__(256)
void transpose_bf16(const u16* __restrict__ in, u16* __restrict__ outp)
{
    __shared__ u16 tile[64][72];
    const int b = blockIdx.z;
    const int s0 = blockIdx.x * 64, d0 = blockIdx.y * 64;
    const int t = threadIdx.x;
    const u16* src = in + ((size_t)b * S_ + s0) * E_ + d0;
    #pragma unroll
    for (int i = 0; i < 2; ++i) {
        const int r = (t >> 3) + i * 32;
        const int c = (t & 7) * 8;
        u16x8 v = *(const u16x8*)(src + (size_t)r * E_ + c);
        #pragma unroll
        for (int e = 0; e < 8; ++e) tile[r][c + e] = v[e];
    }
    __syncthreads();
    u16* dst = outp + ((size_t)b * E_ + d0) * S_ + s0;
    #pragma unroll
    for (int i = 0; i < 2; ++i) {
        const int r = (t >> 3) + i * 32;   // d-row within tile
        const int c = (t & 7) * 8;         // s-col
        u16x8 v;
        #pragma unroll
        for (int e = 0; e < 8; ++e) v[e] = tile[c + e][r];
        *(u16x8*)(dst + (size_t)r * S_ + c) = v;
    }
}

// ---------------------------------------------------------------------------
// Row softmax: read 2048 f32 logits, write 2048 bf16 probabilities.
// One block per row, 256 threads x 8 elements.
// ---------------------------------------------------------------------------
__global__ __launch_bounds__(256)
void softmax_rows(const float* __restrict__ s, u16* __restrict__ pout)
{
    const int t = threadIdx.x;
    const float* row = s + (size_t)blockIdx.x * (size_t)S_;
    float f[8];
    {
        const float4 a = *(const float4*)(row + t * 8);
        const float4 b = *(const float4*)(row + t * 8 + 4);
        f[0] = a.x; f[1] = a.y; f[2] = a.z; f[3] = a.w;
        f[4] = b.x; f[5] = b.y; f[6] = b.z; f[7] = b.w;
    }
    float mx = f[0];
    #pragma unroll
    for (int e = 1; e < 8; ++e) mx = fmaxf(mx, f[e]);
    #pragma unroll
    for (int d = 1; d < 64; d <<= 1) mx = fmaxf(mx, __shfl_xor(mx, d));
    __shared__ float sh[8];
    if ((t & 63) == 0) sh[t >> 6] = mx;
    __syncthreads();
    mx = fmaxf(fmaxf(sh[0], sh[1]), fmaxf(sh[2], sh[3]));
    float sum = 0.f;
    #pragma unroll
    for (int e = 0; e < 8; ++e) { f[e] = __expf(f[e] - mx); sum += f[e]; }
    #pragma unroll
    for (int d = 1; d < 64; d <<= 1) sum += __shfl_xor(sum, d);
    if ((t & 63) == 0) sh[4 + (t >> 6)] = sum;
    __syncthreads();
    sum = sh[4] + sh[5] + sh[6] + sh[7];
    const float inv = 1.f / sum;
    u16x8 v;
    #pragma unroll
    for (int e = 0; e < 8; ++e) v[e] = f2b(f[e] * inv);
    *(u16x8*)(pout + (size_t)blockIdx.x * (size_t)S_ + t * 8) = v;
}

// ---------------------------------------------------------------------------
// Fused residual + LayerNorm (+ optional qf = cos(y[:128] + theta) epilogue).
// One block per row (768 cols, 256 threads x 3).
// ---------------------------------------------------------------------------
__global__ __launch_bounds__(256)
void ln_fuse(const float* __restrict__ a, const float* __restrict__ res,
             const float* __restrict__ g, const float* __restrict__ bb,
             const float* __restrict__ theta, float* __restrict__ out,
             u16* __restrict__ qf)
{
    const int row = blockIdx.x, t = threadIdx.x;
    const float* ar = a + (size_t)row * E_;
    const float* rr = res + (size_t)row * E_;
    float v0 = ar[t] + rr[t];
    float v1 = ar[t + 256] + rr[t + 256];
    float v2 = ar[t + 512] + rr[t + 512];
    float s1 = v0 + v1 + v2;
    float s2 = v0 * v0 + v1 * v1 + v2 * v2;
    #pragma unroll
    for (int d = 1; d < 64; d <<= 1) { s1 += __shfl_xor(s1, d); s2 += __shfl_xor(s2, d); }
    __shared__ float sh[8];
    if ((t & 63) == 0) { sh[t >> 6] = s1; sh[4 + (t >> 6)] = s2; }
    __syncthreads();
    s1 = sh[0] + sh[1] + sh[2] + sh[3];
    s2 = sh[4] + sh[5] + sh[6] + sh[7];
    const float mean = s1 * (1.f / 768.f);
    const float var = s2 * (1.f / 768.f) - mean * mean;
    const float rs = rsqrtf(var + 1e-5f);
    float* orow = out + (size_t)row * E_;
    const float y0 = (v0 - mean) * rs * g[t] + bb[t];
    const float y1 = (v1 - mean) * rs * g[t + 256] + bb[t + 256];
    const float y2 = (v2 - mean) * rs * g[t + 512] + bb[t + 512];
    orow[t] = y0; orow[t + 256] = y1; orow[t + 512] = y2;
    if (qf != nullptr && t < NQ_)
        qf[(size_t)row * NQ_ + t] = f2b(cosf(y0 + theta[t]));
}

// ---------------------------------------------------------------------------
// Workspace arena plan (216 MiB arena + 5.25 MiB fixed tail).
// Timeline:  t0 cvt | t1 gemm0 | t2 transpose | t3 scores | t4 softmax
//            t5 PV  | t6 ln1   | t7 ffn1      | t8 ffn2   | t9 ln2
// buffer   offset(MiB) size  live
//  x_b        0       24    t0-t1
//  Wp_b      24       1.13  t0-t1
//  qa       128       24    t1-t3
//  qaT      192       24    t2-t5
//  scores     0      128    t3-t4
//  probs    128       64    t4-t5
//  ao         0       48    t5-t6,t8-t9
//  x1       144       48    t6-t9
//  qf       192        4    t6-t7
//  h         48       96    t7-t8
// ---------------------------------------------------------------------------
extern "C" void kernel_launch(void* const* d_in, const int* in_sizes, int n_in,
                              void* d_out, int out_size, void* d_ws, size_t ws_size,
                              hipStream_t stream)
{
    (void)in_sizes; (void)n_in; (void)out_size;
    const float* x    = (const float*)d_in[0];
    const float* Wp   = (const float*)d_in[1];
    const float* trx  = (const float*)d_in[2];
    const float* try_ = (const float*)d_in[3];
    const float* W1   = (const float*)d_in[4];
    const float* b1   = (const float*)d_in[5];
    const float* W2   = (const float*)d_in[6];
    const float* b2   = (const float*)d_in[7];
    const float* g1   = (const float*)d_in[8];
    const float* bb1  = (const float*)d_in[9];
    const float* g2   = (const float*)d_in[10];
    const float* bb2  = (const float*)d_in[11];
    float* out = (float*)d_out;

    const size_t MiB = (size_t)1 << 20;
    char* arena = (char*)d_ws;
    u16*   x_b    = (u16*)  (arena + 0);
    u16*   Wp_b   = (u16*)  (arena + 24 * MiB);
    u16*   qa     = (u16*)  (arena + 128 * MiB);
    u16*   qaT    = (u16*)  (arena + 192 * MiB);
    float* scores = (float*)(arena + 0);
    u16*   probs  = (u16*)  (arena + 128 * MiB);
    float* ao     = (float*)(arena + 0);
    float* x1     = (float*)(arena + 144 * MiB);
    u16*   qf     = (u16*)  (arena + 192 * MiB);
    u16*   h      = (u16*)  (arena + 48 * MiB);
    u16*   W1_b   = (u16*)  (arena + 216 * MiB);
    u16*   W2_b   = (u16*)  (arena + 216 * MiB + (size_t)FF_ * NQ_ * 2);
    const size_t need = 216 * MiB + (size_t)FF_ * NQ_ * 2 + (size_t)E_ * FF_ * 2;
    if (need > ws_size) {
        fprintf(stderr, "kernel_launch: ws too small: need=%zu have=%zu\n", need, ws_size);
        return;
    }

    cvt_bf16<<<512, 256, 0, stream>>>(x,  x_b,  BS_ * E_);
    cvt_bf16<<<64,  256, 0, stream>>>(Wp, Wp_b, E_ * E_);
    cvt_bf16<<<64,  256, 0, stream>>>(W1, W1_b, FF_ * NQ_);
    cvt_bf16<<<64,  256, 0, stream>>>(W2, W2_b, E_ * FF_);

    // qa = cos(x @ Wp^T + theta_rx)
    gemm_bt<E_, 0><<<dim3(BS_ / 128, E_ / 128), 256, 0, stream>>>(
        x_b, Wp_b, trx, qa, E_, 0, 0, 0);
    // qaT[b][d][s] = qa[b][s][d]
    transpose_bf16<<<dim3(S_ / 64, E_ / 64, B_), 256, 0, stream>>>(qa, qaT);
    // scores = (qa @ qa^T) / sqrt(8), f32 NT, per batch
    gemm_bt<E_, 4><<<dim3(S_ / 128, S_ / 128, B_), 256, 0, stream>>>(
        qa, qa, nullptr, scores, S_,
        (size_t)S_ * E_, (size_t)S_ * E_, (size_t)S_ * S_);
    // probs = softmax(scores) in bf16
    softmax_rows<<<BS_, 256, 0, stream>>>(scores, probs);
    // ao = probs @ qa  (= probs [S,S] * qaT [E,S]^T), f32 NT, per batch
    gemm_bt<S_, 3><<<dim3(S_ / 128, E_ / 128, B_), 256, 0, stream>>>(
        probs, qaT, nullptr, ao, E_,
        (size_t)S_ * S_, (size_t)E_ * S_, (size_t)S_ * E_);

    ln_fuse<<<BS_, 256, 0, stream>>>(ao, x, g1, bb1, try_, x1, qf);
    // SWAP: grid (ntiles, mtiles) so each XCD owns a contiguous M-range
    gemm_bt<NQ_, 1, true><<<dim3(FF_ / 128, BS_ / 128), 256, 0, stream>>>(
        qf, W1_b, b1, h, FF_, 0, 0, 0);
    gemm_bt<FF_, 2, true><<<dim3(E_ / 128, BS_ / 128), 256, 0, stream>>>(
        h, W2_b, b2, ao, E_, 0, 0, 0);
    ln_fuse<<<BS_, 256, 0, stream>>>(ao, x1, g2, bb2, nullptr, out, nullptr);
}

// Round 5
// 884.223 us; speedup vs baseline: 1.0600x; 1.0600x over previous
//
#include <hip/hip_runtime.h>
#include <hip/hip_bf16.h>
#include <cstdio>
#include <cstdint>

typedef __bf16 bf16x8 __attribute__((ext_vector_type(8)));
typedef unsigned short u16;
typedef u16 u16x8 __attribute__((ext_vector_type(8)));
typedef float f32x4 __attribute__((ext_vector_type(4)));

#define DEV __device__ __forceinline__

static constexpr int B_ = 8, S_ = 2048, E_ = 768, NQ_ = 128, FF_ = 3072;
static constexpr int BS_ = B_ * S_;

DEV u16 f2b(float f) {
    unsigned u = __builtin_bit_cast(unsigned, f);
    unsigned r = (u + 0x7fffu + ((u >> 16) & 1u)) >> 16;
    return (u16)r;
}

DEV f32x4 mfma16(bf16x8 a, bf16x8 b, f32x4 c) {
    return __builtin_amdgcn_mfma_f32_16x16x32_bf16(a, b, c, 0, 0, 0);
}

#define GLD16(gp, lp) __builtin_amdgcn_global_load_lds( \
    (const __attribute__((address_space(1))) void*)(gp), \
    (__attribute__((address_space(3))) void*)(lp), 16, 0, 0)

// ---------------------------------------------------------------------------
// f32 -> bf16 convert (vectorized float4 -> ushort4)
// ---------------------------------------------------------------------------
__global__ void cvt_bf16(const float* __restrict__ in, u16* __restrict__ out, int n)
{
    const int stride = gridDim.x * blockDim.x * 4;
    for (int i = (blockIdx.x * blockDim.x + threadIdx.x) * 4; i < n; i += stride) {
        const float4 f = *(const float4*)(in + i);
        ushort4 u;
        u.x = f2b(f.x); u.y = f2b(f.y); u.z = f2b(f.z); u.w = f2b(f.w);
        *(ushort4*)(out + i) = u;
    }
}

// ---------------------------------------------------------------------------
// Templated (optionally batched) GEMM: C[M,N] = A[M,K] * B[N,K]^T
// 256x256 tile, BK=64, 8 waves (2x4 of 128x64), 512 threads,
// global_load_lds staging with XOR-swizzled LDS (inverse swizzle applied to
// the global source address).  Tile doubled from 128 -> 256 to HALVE panel
// traffic: rounds 2-4 showed the K-deep GEMMs pinned at ~4.1 TB/s effective
// with zero-reuse panel traffic regardless of block order / store path, so
// the fix is arithmetic (reads scale as 1/tile).
//
// blockIdx.z = batch; sA/sB/sC are per-batch element strides (0 if unbatched).
// MODE 0: out bf16 = cos(c + bias[col])       (qa)
// MODE 1: out bf16 = relu(c + bias[col])      (h)
// MODE 2: out f32  = c + bias[col]            (ffn)
// MODE 3: out f32  = c                        (attn @ qa)
// MODE 4: out f32  = c * (1/sqrt(8))          (scores -- f32! logits need
//                                              more than bf16 precision)
// ---------------------------------------------------------------------------
template<int K, int MODE>
__global__ __launch_bounds__(512)
void gemm_bt(const u16* __restrict__ A, const u16* __restrict__ Bm,
             const float* __restrict__ bias, void* __restrict__ out, int N,
             size_t sA, size_t sB, size_t sC)
{
    __shared__ u16 As[256 * 64];   // 32 KiB
    __shared__ u16 Bs[256 * 64];   // 32 KiB
    const int t = threadIdx.x;
    const int w = t >> 6, lane = t & 63;
    const int m0 = blockIdx.x * 256, n0 = blockIdx.y * 256;
    const int wr = w >> 2, wc = w & 3;      // 2 x 4 waves; wave tile 128x64
    A  += (size_t)blockIdx.z * sA;
    Bm += (size_t)blockIdx.z * sB;
    u16*   ob16 = (u16*)out   + (size_t)blockIdx.z * sC;
    float* of32 = (float*)out + (size_t)blockIdx.z * sC;
    f32x4 acc[8][4] = {};

    for (int k0 = 0; k0 < K; k0 += 64) {
        __syncthreads();
        #pragma unroll
        for (int r = 0; r < 4; ++r) {
            const int ci = r * 512 + t;
            const int row = ci >> 3;                       // 0..255
            const int colb = ((ci & 7) * 16) ^ ((row & 7) << 4);
            GLD16(A  + (size_t)(m0 + row) * K + k0 + (colb >> 1),
                  As + (size_t)(r * 512 + w * 64) * 8);
            GLD16(Bm + (size_t)(n0 + row) * K + k0 + (colb >> 1),
                  Bs + (size_t)(r * 512 + w * 64) * 8);
        }
        __syncthreads();
        #pragma unroll
        for (int kk = 0; kk < 2; ++kk) {
            bf16x8 af[8], bf[4];
            const int cb = kk * 64 + ((lane >> 4) << 4);   // byte offset in row
            #pragma unroll
            for (int m = 0; m < 8; ++m) {
                const int row = wr * 128 + m * 16 + (lane & 15);
                af[m] = *(const bf16x8*)((const char*)As + row * 128 + (cb ^ ((row & 7) << 4)));
            }
            #pragma unroll
            for (int n = 0; n < 4; ++n) {
                const int row = wc * 64 + n * 16 + (lane & 15);
                bf[n] = *(const bf16x8*)((const char*)Bs + row * 128 + (cb ^ ((row & 7) << 4)));
            }
            #pragma unroll
            for (int m = 0; m < 8; ++m)
                #pragma unroll
                for (int n = 0; n < 4; ++n)
                    acc[m][n] = mfma16(af[m], bf[n], acc[m][n]);
        }
    }
    // epilogue: C/D layout col = lane&15, row = (lane>>4)*4 + r
    #pragma unroll
    for (int m = 0; m < 8; ++m) {
        const int rowb = m0 + wr * 128 + m * 16 + ((lane >> 4) << 2);
        #pragma unroll
        for (int n = 0; n < 4; ++n) {
            const int col = n0 + wc * 64 + n * 16 + (lane & 15);
            float bv = 0.f;
            if (MODE == 0 || MODE == 1 || MODE == 2) bv = bias[col];
            #pragma unroll
            for (int r = 0; r < 4; ++r) {
                const float c = acc[m][n][r];
                const size_t idx = (size_t)(rowb + r) * N + col;
                if (MODE == 0)      ob16[idx] = f2b(cosf(c + bv));
                else if (MODE == 1) ob16[idx] = f2b(fmaxf(c + bv, 0.f));
                else if (MODE == 2) of32[idx] = c + bv;
                else if (MODE == 3) of32[idx] = c;
                else                of32[idx] = c * 0.35355339059327373f;
            }
        }
    }
}

// ---------------------------------------------------------------------------
// Tiled bf16 transpose: in [B][S][E] -> out [B][E][S], 64x64 tiles.
// ---------------------------------------------------------------------------
__global__ __launch_bounds__(256)
void transpose_bf16(const u16* __restrict__ in, u16* __restrict__ outp)
{
    __shared__ u16 tile[64][72];
    const int b = blockIdx.z;
    const int s0 = blockIdx.x * 64, d0 = blockIdx.y * 64;
    const int t = threadIdx.x;
    const u16* src = in + ((size_t)b * S_ + s0) * E_ + d0;
    #pragma unroll
    for (int i = 0; i < 2; ++i) {
        const int r = (t >> 3) + i * 32;
        const int c = (t & 7) * 8;
        u16x8 v = *(const u16x8*)(src + (size_t)r * E_ + c);
        #pragma unroll
        for (int e = 0; e < 8; ++e) tile[r][c + e] = v[e];
    }
    __syncthreads();
    u16* dst = outp + ((size_t)b * E_ + d0) * S_ + s0;
    #pragma unroll
    for (int i = 0; i < 2; ++i) {
        const int r = (t >> 3) + i * 32;   // d-row within tile
        const int c = (t & 7) * 8;         // s-col
        u16x8 v;
        #pragma unroll
        for (int e = 0; e < 8; ++e) v[e] = tile[c + e][r];
        *(u16x8*)(dst + (size_t)r * S_ + c) = v;
    }
}

// ---------------------------------------------------------------------------
// Row softmax: read 2048 f32 logits, write 2048 bf16 probabilities.
// One block per row, 256 threads x 8 elements.
// ---------------------------------------------------------------------------
__global__ __launch_bounds__(256)
void softmax_rows(const float* __restrict__ s, u16* __restrict__ pout)
{
    const int t = threadIdx.x;
    const float* row = s + (size_t)blockIdx.x * (size_t)S_;
    float f[8];
    {
        const float4 a = *(const float4*)(row + t * 8);
        const float4 b = *(const float4*)(row + t * 8 + 4);
        f[0] = a.x; f[1] = a.y; f[2] = a.z; f[3] = a.w;
        f[4] = b.x; f[5] = b.y; f[6] = b.z; f[7] = b.w;
    }
    float mx = f[0];
    #pragma unroll
    for (int e = 1; e < 8; ++e) mx = fmaxf(mx, f[e]);
    #pragma unroll
    for (int d = 1; d < 64; d <<= 1) mx = fmaxf(mx, __shfl_xor(mx, d));
    __shared__ float sh[8];
    if ((t & 63) == 0) sh[t >> 6] = mx;
    __syncthreads();
    mx = fmaxf(fmaxf(sh[0], sh[1]), fmaxf(sh[2], sh[3]));
    float sum = 0.f;
    #pragma unroll
    for (int e = 0; e < 8; ++e) { f[e] = __expf(f[e] - mx); sum += f[e]; }
    #pragma unroll
    for (int d = 1; d < 64; d <<= 1) sum += __shfl_xor(sum, d);
    if ((t & 63) == 0) sh[4 + (t >> 6)] = sum;
    __syncthreads();
    sum = sh[4] + sh[5] + sh[6] + sh[7];
    const float inv = 1.f / sum;
    u16x8 v;
    #pragma unroll
    for (int e = 0; e < 8; ++e) v[e] = f2b(f[e] * inv);
    *(u16x8*)(pout + (size_t)blockIdx.x * (size_t)S_ + t * 8) = v;
}

// ---------------------------------------------------------------------------
// Fused residual + LayerNorm (+ optional qf = cos(y[:128] + theta) epilogue).
// One block per row (768 cols, 256 threads x 3).
// ---------------------------------------------------------------------------
__global__ __launch_bounds__(256)
void ln_fuse(const float* __restrict__ a, const float* __restrict__ res,
             const float* __restrict__ g, const float* __restrict__ bb,
             const float* __restrict__ theta, float* __restrict__ out,
             u16* __restrict__ qf)
{
    const int row = blockIdx.x, t = threadIdx.x;
    const float* ar = a + (size_t)row * E_;
    const float* rr = res + (size_t)row * E_;
    float v0 = ar[t] + rr[t];
    float v1 = ar[t + 256] + rr[t + 256];
    float v2 = ar[t + 512] + rr[t + 512];
    float s1 = v0 + v1 + v2;
    float s2 = v0 * v0 + v1 * v1 + v2 * v2;
    #pragma unroll
    for (int d = 1; d < 64; d <<= 1) { s1 += __shfl_xor(s1, d); s2 += __shfl_xor(s2, d); }
    __shared__ float sh[8];
    if ((t & 63) == 0) { sh[t >> 6] = s1; sh[4 + (t >> 6)] = s2; }
    __syncthreads();
    s1 = sh[0] + sh[1] + sh[2] + sh[3];
    s2 = sh[4] + sh[5] + sh[6] + sh[7];
    const float mean = s1 * (1.f / 768.f);
    const float var = s2 * (1.f / 768.f) - mean * mean;
    const float rs = rsqrtf(var + 1e-5f);
    float* orow = out + (size_t)row * E_;
    const float y0 = (v0 - mean) * rs * g[t] + bb[t];
    const float y1 = (v1 - mean) * rs * g[t + 256] + bb[t + 256];
    const float y2 = (v2 - mean) * rs * g[t + 512] + bb[t + 512];
    orow[t] = y0; orow[t + 256] = y1; orow[t + 512] = y2;
    if (qf != nullptr && t < NQ_)
        qf[(size_t)row * NQ_ + t] = f2b(cosf(y0 + theta[t]));
}

// ---------------------------------------------------------------------------
// Workspace arena plan (216 MiB arena + 5.25 MiB fixed tail).
// Timeline:  t0 cvt | t1 gemm0 | t2 transpose | t3 scores | t4 softmax
//            t5 PV  | t6 ln1   | t7 ffn1      | t8 ffn2   | t9 ln2
// buffer   offset(MiB) size  live
//  x_b        0       24    t0-t1
//  Wp_b      24       1.13  t0-t1
//  qa       128       24    t1-t3
//  qaT      192       24    t2-t5
//  scores     0      128    t3-t4
//  probs    128       64    t4-t5
//  ao         0       48    t5-t6,t8-t9
//  x1       144       48    t6-t9
//  qf       192        4    t6-t7
//  h         48       96    t7-t8
// ---------------------------------------------------------------------------
extern "C" void kernel_launch(void* const* d_in, const int* in_sizes, int n_in,
                              void* d_out, int out_size, void* d_ws, size_t ws_size,
                              hipStream_t stream)
{
    (void)in_sizes; (void)n_in; (void)out_size;
    const float* x    = (const float*)d_in[0];
    const float* Wp   = (const float*)d_in[1];
    const float* trx  = (const float*)d_in[2];
    const float* try_ = (const float*)d_in[3];
    const float* W1   = (const float*)d_in[4];
    const float* b1   = (const float*)d_in[5];
    const float* W2   = (const float*)d_in[6];
    const float* b2   = (const float*)d_in[7];
    const float* g1   = (const float*)d_in[8];
    const float* bb1  = (const float*)d_in[9];
    const float* g2   = (const float*)d_in[10];
    const float* bb2  = (const float*)d_in[11];
    float* out = (float*)d_out;

    const size_t MiB = (size_t)1 << 20;
    char* arena = (char*)d_ws;
    u16*   x_b    = (u16*)  (arena + 0);
    u16*   Wp_b   = (u16*)  (arena + 24 * MiB);
    u16*   qa     = (u16*)  (arena + 128 * MiB);
    u16*   qaT    = (u16*)  (arena + 192 * MiB);
    float* scores = (float*)(arena + 0);
    u16*   probs  = (u16*)  (arena + 128 * MiB);
    float* ao     = (float*)(arena + 0);
    float* x1     = (float*)(arena + 144 * MiB);
    u16*   qf     = (u16*)  (arena + 192 * MiB);
    u16*   h      = (u16*)  (arena + 48 * MiB);
    u16*   W1_b   = (u16*)  (arena + 216 * MiB);
    u16*   W2_b   = (u16*)  (arena + 216 * MiB + (size_t)FF_ * NQ_ * 2);
    const size_t need = 216 * MiB + (size_t)FF_ * NQ_ * 2 + (size_t)E_ * FF_ * 2;
    if (need > ws_size) {
        fprintf(stderr, "kernel_launch: ws too small: need=%zu have=%zu\n", need, ws_size);
        return;
    }

    cvt_bf16<<<512, 256, 0, stream>>>(x,  x_b,  BS_ * E_);
    cvt_bf16<<<64,  256, 0, stream>>>(Wp, Wp_b, E_ * E_);
    cvt_bf16<<<64,  256, 0, stream>>>(W1, W1_b, FF_ * NQ_);
    cvt_bf16<<<64,  256, 0, stream>>>(W2, W2_b, E_ * FF_);

    // qa = cos(x @ Wp^T + theta_rx)
    gemm_bt<E_, 0><<<dim3(BS_ / 256, E_ / 256), 512, 0, stream>>>(
        x_b, Wp_b, trx, qa, E_, 0, 0, 0);
    // qaT[b][d][s] = qa[b][s][d]
    transpose_bf16<<<dim3(S_ / 64, E_ / 64, B_), 256, 0, stream>>>(qa, qaT);
    // scores = (qa @ qa^T) / sqrt(8), f32, per batch
    gemm_bt<E_, 4><<<dim3(S_ / 256, S_ / 256, B_), 512, 0, stream>>>(
        qa, qa, nullptr, scores, S_,
        (size_t)S_ * E_, (size_t)S_ * E_, (size_t)S_ * S_);
    // probs = softmax(scores) in bf16
    softmax_rows<<<BS_, 256, 0, stream>>>(scores, probs);
    // ao = probs @ qa  (= probs [S,S] * qaT [E,S]^T), f32, per batch
    gemm_bt<S_, 3><<<dim3(S_ / 256, E_ / 256, B_), 512, 0, stream>>>(
        probs, qaT, nullptr, ao, E_,
        (size_t)S_ * S_, (size_t)E_ * S_, (size_t)S_ * E_);

    ln_fuse<<<BS_, 256, 0, stream>>>(ao, x, g1, bb1, try_, x1, qf);
    gemm_bt<NQ_, 1><<<dim3(BS_ / 256, FF_ / 256), 512, 0, stream>>>(
        qf, W1_b, b1, h, FF_, 0, 0, 0);
    gemm_bt<FF_, 2><<<dim3(BS_ / 256, E_ / 256), 512, 0, stream>>>(
        h, W2_b, b2, ao, E_, 0, 0, 0);
    ln_fuse<<<BS_, 256, 0, stream>>>(ao, x1, g2, bb2, nullptr, out, nullptr);
}

// Round 6
// 882.336 us; speedup vs baseline: 1.0623x; 1.0021x over previous
//
#include <hip/hip_runtime.h>
#include <hip/hip_bf16.h>
#include <cstdio>
#include <cstdint>

typedef __bf16 bf16x8 __attribute__((ext_vector_type(8)));
typedef unsigned short u16;
typedef u16 u16x8 __attribute__((ext_vector_type(8)));
typedef float f32x4 __attribute__((ext_vector_type(4)));

#define DEV __device__ __forceinline__

static constexpr int B_ = 8, S_ = 2048, E_ = 768, NQ_ = 128, FF_ = 3072;
static constexpr int BS_ = B_ * S_;

DEV u16 f2b(float f) {
    unsigned u = __builtin_bit_cast(unsigned, f);
    unsigned r = (u + 0x7fffu + ((u >> 16) & 1u)) >> 16;
    return (u16)r;
}

DEV f32x4 mfma16(bf16x8 a, bf16x8 b, f32x4 c) {
    return __builtin_amdgcn_mfma_f32_16x16x32_bf16(a, b, c, 0, 0, 0);
}

#define GLD16(gp, lp) __builtin_amdgcn_global_load_lds( \
    (const __attribute__((address_space(1))) void*)(gp), \
    (__attribute__((address_space(3))) void*)(lp), 16, 0, 0)

// ---------------------------------------------------------------------------
// f32 -> bf16 convert (vectorized float4 -> ushort4)
// ---------------------------------------------------------------------------
__global__ void cvt_bf16(const float* __restrict__ in, u16* __restrict__ out, int n)
{
    const int stride = gridDim.x * blockDim.x * 4;
    for (int i = (blockIdx.x * blockDim.x + threadIdx.x) * 4; i < n; i += stride) {
        const float4 f = *(const float4*)(in + i);
        ushort4 u;
        u.x = f2b(f.x); u.y = f2b(f.y); u.z = f2b(f.z); u.w = f2b(f.w);
        *(ushort4*)(out + i) = u;
    }
}

// ---------------------------------------------------------------------------
// Templated (optionally batched) GEMM: C[M,N] = A[M,K] * B[N,K]^T
// 256x256 tile, BK=64, 8 waves (2x4 of 128x64), 512 threads,
// global_load_lds staging with XOR-swizzled LDS (inverse swizzle applied to
// the global source address).
//
// __launch_bounds__(512, 2): round-5 counters showed VGPR_Count=52 against a
// 128-float accumulator -> the compiler register-capped for max occupancy and
// SPILLED the accumulator to scratch (WRITE_SIZE 1.25 GB vs 134 MB unique
// output, dur 410us).  2 waves/EU min = 1 block/CU = 256 VGPR cap; true need
// ~196 (128 acc + 48 operands + addressing) -> no spill.
//
// blockIdx.z = batch; sA/sB/sC are per-batch element strides (0 if unbatched).
// MODE 0: out bf16 = cos(c + bias[col])       (qa)
// MODE 1: out bf16 = relu(c + bias[col])      (h)
// MODE 2: out f32  = c + bias[col]            (ffn)
// MODE 3: out f32  = c                        (attn @ qa)
// MODE 4: out f32  = c * (1/sqrt(8))          (scores -- f32! logits need
//                                              more than bf16 precision)
// ---------------------------------------------------------------------------
template<int K, int MODE>
__global__ __launch_bounds__(512, 2)
void gemm_bt(const u16* __restrict__ A, const u16* __restrict__ Bm,
             const float* __restrict__ bias, void* __restrict__ out, int N,
             size_t sA, size_t sB, size_t sC)
{
    __shared__ u16 As[256 * 64];   // 32 KiB
    __shared__ u16 Bs[256 * 64];   // 32 KiB
    const int t = threadIdx.x;
    const int w = t >> 6, lane = t & 63;
    const int m0 = blockIdx.x * 256, n0 = blockIdx.y * 256;
    const int wr = w >> 2, wc = w & 3;      // 2 x 4 waves; wave tile 128x64
    A  += (size_t)blockIdx.z * sA;
    Bm += (size_t)blockIdx.z * sB;
    u16*   ob16 = (u16*)out   + (size_t)blockIdx.z * sC;
    float* of32 = (float*)out + (size_t)blockIdx.z * sC;
    f32x4 acc[8][4] = {};

    for (int k0 = 0; k0 < K; k0 += 64) {
        __syncthreads();
        #pragma unroll
        for (int r = 0; r < 4; ++r) {
            const int ci = r * 512 + t;
            const int row = ci >> 3;                       // 0..255
            const int colb = ((ci & 7) * 16) ^ ((row & 7) << 4);
            GLD16(A  + (size_t)(m0 + row) * K + k0 + (colb >> 1),
                  As + (size_t)(r * 512 + w * 64) * 8);
            GLD16(Bm + (size_t)(n0 + row) * K + k0 + (colb >> 1),
                  Bs + (size_t)(r * 512 + w * 64) * 8);
        }
        __syncthreads();
        #pragma unroll
        for (int kk = 0; kk < 2; ++kk) {
            bf16x8 af[8], bf[4];
            const int cb = kk * 64 + ((lane >> 4) << 4);   // byte offset in row
            #pragma unroll
            for (int m = 0; m < 8; ++m) {
                const int row = wr * 128 + m * 16 + (lane & 15);
                af[m] = *(const bf16x8*)((const char*)As + row * 128 + (cb ^ ((row & 7) << 4)));
            }
            #pragma unroll
            for (int n = 0; n < 4; ++n) {
                const int row = wc * 64 + n * 16 + (lane & 15);
                bf[n] = *(const bf16x8*)((const char*)Bs + row * 128 + (cb ^ ((row & 7) << 4)));
            }
            #pragma unroll
            for (int m = 0; m < 8; ++m)
                #pragma unroll
                for (int n = 0; n < 4; ++n)
                    acc[m][n] = mfma16(af[m], bf[n], acc[m][n]);
        }
    }
    // epilogue: C/D layout col = lane&15, row = (lane>>4)*4 + r
    #pragma unroll
    for (int m = 0; m < 8; ++m) {
        const int rowb = m0 + wr * 128 + m * 16 + ((lane >> 4) << 2);
        #pragma unroll
        for (int n = 0; n < 4; ++n) {
            const int col = n0 + wc * 64 + n * 16 + (lane & 15);
            float bv = 0.f;
            if (MODE == 0 || MODE == 1 || MODE == 2) bv = bias[col];
            #pragma unroll
            for (int r = 0; r < 4; ++r) {
                const float c = acc[m][n][r];
                const size_t idx = (size_t)(rowb + r) * N + col;
                if (MODE == 0)      ob16[idx] = f2b(cosf(c + bv));
                else if (MODE == 1) ob16[idx] = f2b(fmaxf(c + bv, 0.f));
                else if (MODE == 2) of32[idx] = c + bv;
                else if (MODE == 3) of32[idx] = c;
                else                of32[idx] = c * 0.35355339059327373f;
            }
        }
    }
}

// ---------------------------------------------------------------------------
// Tiled bf16 transpose: in [B][S][E] -> out [B][E][S], 64x64 tiles.
// ---------------------------------------------------------------------------
__global__ __launch_bounds__(256)
void transpose_bf16(const u16* __restrict__ in, u16* __restrict__ outp)
{
    __shared__ u16 tile[64][72];
    const int b = blockIdx.z;
    const int s0 = blockIdx.x * 64, d0 = blockIdx.y * 64;
    const int t = threadIdx.x;
    const u16* src = in + ((size_t)b * S_ + s0) * E_ + d0;
    #pragma unroll
    for (int i = 0; i < 2; ++i) {
        const int r = (t >> 3) + i * 32;
        const int c = (t & 7) * 8;
        u16x8 v = *(const u16x8*)(src + (size_t)r * E_ + c);
        #pragma unroll
        for (int e = 0; e < 8; ++e) tile[r][c + e] = v[e];
    }
    __syncthreads();
    u16* dst = outp + ((size_t)b * E_ + d0) * S_ + s0;
    #pragma unroll
    for (int i = 0; i < 2; ++i) {
        const int r = (t >> 3) + i * 32;   // d-row within tile
        const int c = (t & 7) * 8;         // s-col
        u16x8 v;
        #pragma unroll
        for (int e = 0; e < 8; ++e) v[e] = tile[c + e][r];
        *(u16x8*)(dst + (size_t)r * S_ + c) = v;
    }
}

// ---------------------------------------------------------------------------
// Row softmax: read 2048 f32 logits, write 2048 bf16 probabilities.
// One block per row, 256 threads x 8 elements.
// ---------------------------------------------------------------------------
__global__ __launch_bounds__(256)
void softmax_rows(const float* __restrict__ s, u16* __restrict__ pout)
{
    const int t = threadIdx.x;
    const float* row = s + (size_t)blockIdx.x * (size_t)S_;
    float f[8];
    {
        const float4 a = *(const float4*)(row + t * 8);
        const float4 b = *(const float4*)(row + t * 8 + 4);
        f[0] = a.x; f[1] = a.y; f[2] = a.z; f[3] = a.w;
        f[4] = b.x; f[5] = b.y; f[6] = b.z; f[7] = b.w;
    }
    float mx = f[0];
    #pragma unroll
    for (int e = 1; e < 8; ++e) mx = fmaxf(mx, f[e]);
    #pragma unroll
    for (int d = 1; d < 64; d <<= 1) mx = fmaxf(mx, __shfl_xor(mx, d));
    __shared__ float sh[8];
    if ((t & 63) == 0) sh[t >> 6] = mx;
    __syncthreads();
    mx = fmaxf(fmaxf(sh[0], sh[1]), fmaxf(sh[2], sh[3]));
    float sum = 0.f;
    #pragma unroll
    for (int e = 0; e < 8; ++e) { f[e] = __expf(f[e] - mx); sum += f[e]; }
    #pragma unroll
    for (int d = 1; d < 64; d <<= 1) sum += __shfl_xor(sum, d);
    if ((t & 63) == 0) sh[4 + (t >> 6)] = sum;
    __syncthreads();
    sum = sh[4] + sh[5] + sh[6] + sh[7];
    const float inv = 1.f / sum;
    u16x8 v;
    #pragma unroll
    for (int e = 0; e < 8; ++e) v[e] = f2b(f[e] * inv);
    *(u16x8*)(pout + (size_t)blockIdx.x * (size_t)S_ + t * 8) = v;
}

// ---------------------------------------------------------------------------
// Fused residual + LayerNorm (+ optional qf = cos(y[:128] + theta) epilogue).
// One block per row (768 cols, 256 threads x 3).
// ---------------------------------------------------------------------------
__global__ __launch_bounds__(256)
void ln_fuse(const float* __restrict__ a, const float* __restrict__ res,
             const float* __restrict__ g, const float* __restrict__ bb,
             const float* __restrict__ theta, float* __restrict__ out,
             u16* __restrict__ qf)
{
    const int row = blockIdx.x, t = threadIdx.x;
    const float* ar = a + (size_t)row * E_;
    const float* rr = res + (size_t)row * E_;
    float v0 = ar[t] + rr[t];
    float v1 = ar[t + 256] + rr[t + 256];
    float v2 = ar[t + 512] + rr[t + 512];
    float s1 = v0 + v1 + v2;
    float s2 = v0 * v0 + v1 * v1 + v2 * v2;
    #pragma unroll
    for (int d = 1; d < 64; d <<= 1) { s1 += __shfl_xor(s1, d); s2 += __shfl_xor(s2, d); }
    __shared__ float sh[8];
    if ((t & 63) == 0) { sh[t >> 6] = s1; sh[4 + (t >> 6)] = s2; }
    __syncthreads();
    s1 = sh[0] + sh[1] + sh[2] + sh[3];
    s2 = sh[4] + sh[5] + sh[6] + sh[7];
    const float mean = s1 * (1.f / 768.f);
    const float var = s2 * (1.f / 768.f) - mean * mean;
    const float rs = rsqrtf(var + 1e-5f);
    float* orow = out + (size_t)row * E_;
    const float y0 = (v0 - mean) * rs * g[t] + bb[t];
    const float y1 = (v1 - mean) * rs * g[t + 256] + bb[t + 256];
    const float y2 = (v2 - mean) * rs * g[t + 512] + bb[t + 512];
    orow[t] = y0; orow[t + 256] = y1; orow[t + 512] = y2;
    if (qf != nullptr && t < NQ_)
        qf[(size_t)row * NQ_ + t] = f2b(cosf(y0 + theta[t]));
}

// ---------------------------------------------------------------------------
// Workspace arena plan (216 MiB arena + 5.25 MiB fixed tail).
// Timeline:  t0 cvt | t1 gemm0 | t2 transpose | t3 scores | t4 softmax
//            t5 PV  | t6 ln1   | t7 ffn1      | t8 ffn2   | t9 ln2
// buffer   offset(MiB) size  live
//  x_b        0       24    t0-t1
//  Wp_b      24       1.13  t0-t1
//  qa       128       24    t1-t3
//  qaT      192       24    t2-t5
//  scores     0      128    t3-t4
//  probs    128       64    t4-t5
//  ao         0       48    t5-t6,t8-t9
//  x1       144       48    t6-t9
//  qf       192        4    t6-t7
//  h         48       96    t7-t8
// ---------------------------------------------------------------------------
extern "C" void kernel_launch(void* const* d_in, const int* in_sizes, int n_in,
                              void* d_out, int out_size, void* d_ws, size_t ws_size,
                              hipStream_t stream)
{
    (void)in_sizes; (void)n_in; (void)out_size;
    const float* x    = (const float*)d_in[0];
    const float* Wp   = (const float*)d_in[1];
    const float* trx  = (const float*)d_in[2];
    const float* try_ = (const float*)d_in[3];
    const float* W1   = (const float*)d_in[4];
    const float* b1   = (const float*)d_in[5];
    const float* W2   = (const float*)d_in[6];
    const float* b2   = (const float*)d_in[7];
    const float* g1   = (const float*)d_in[8];
    const float* bb1  = (const float*)d_in[9];
    const float* g2   = (const float*)d_in[10];
    const float* bb2  = (const float*)d_in[11];
    float* out = (float*)d_out;

    const size_t MiB = (size_t)1 << 20;
    char* arena = (char*)d_ws;
    u16*   x_b    = (u16*)  (arena + 0);
    u16*   Wp_b   = (u16*)  (arena + 24 * MiB);
    u16*   qa     = (u16*)  (arena + 128 * MiB);
    u16*   qaT    = (u16*)  (arena + 192 * MiB);
    float* scores = (float*)(arena + 0);
    u16*   probs  = (u16*)  (arena + 128 * MiB);
    float* ao     = (float*)(arena + 0);
    float* x1     = (float*)(arena + 144 * MiB);
    u16*   qf     = (u16*)  (arena + 192 * MiB);
    u16*   h      = (u16*)  (arena + 48 * MiB);
    u16*   W1_b   = (u16*)  (arena + 216 * MiB);
    u16*   W2_b   = (u16*)  (arena + 216 * MiB + (size_t)FF_ * NQ_ * 2);
    const size_t need = 216 * MiB + (size_t)FF_ * NQ_ * 2 + (size_t)E_ * FF_ * 2;
    if (need > ws_size) {
        fprintf(stderr, "kernel_launch: ws too small: need=%zu have=%zu\n", need, ws_size);
        return;
    }

    cvt_bf16<<<512, 256, 0, stream>>>(x,  x_b,  BS_ * E_);
    cvt_bf16<<<64,  256, 0, stream>>>(Wp, Wp_b, E_ * E_);
    cvt_bf16<<<64,  256, 0, stream>>>(W1, W1_b, FF_ * NQ_);
    cvt_bf16<<<64,  256, 0, stream>>>(W2, W2_b, E_ * FF_);

    // qa = cos(x @ Wp^T + theta_rx)
    gemm_bt<E_, 0><<<dim3(BS_ / 256, E_ / 256), 512, 0, stream>>>(
        x_b, Wp_b, trx, qa, E_, 0, 0, 0);
    // qaT[b][d][s] = qa[b][s][d]
    transpose_bf16<<<dim3(S_ / 64, E_ / 64, B_), 256, 0, stream>>>(qa, qaT);
    // scores = (qa @ qa^T) / sqrt(8), f32, per batch
    gemm_bt<E_, 4><<<dim3(S_ / 256, S_ / 256, B_), 512, 0, stream>>>(
        qa, qa, nullptr, scores, S_,
        (size_t)S_ * E_, (size_t)S_ * E_, (size_t)S_ * S_);
    // probs = softmax(scores) in bf16
    softmax_rows<<<BS_, 256, 0, stream>>>(scores, probs);
    // ao = probs @ qa  (= probs [S,S] * qaT [E,S]^T), f32, per batch
    gemm_bt<S_, 3><<<dim3(S_ / 256, E_ / 256, B_), 512, 0, stream>>>(
        probs, qaT, nullptr, ao, E_,
        (size_t)S_ * S_, (size_t)E_ * S_, (size_t)S_ * E_);

    ln_fuse<<<BS_, 256, 0, stream>>>(ao, x, g1, bb1, try_, x1, qf);
    gemm_bt<NQ_, 1><<<dim3(BS_ / 256, FF_ / 256), 512, 0, stream>>>(
        qf, W1_b, b1, h, FF_, 0, 0, 0);
    gemm_bt<FF_, 2><<<dim3(BS_ / 256, E_ / 256), 512, 0, stream>>>(
        h, W2_b, b2, ao, E_, 0, 0, 0);
    ln_fuse<<<BS_, 256, 0, stream>>>(ao, x1, g2, bb2, nullptr, out, nullptr);
}

// Round 8
// 614.116 us; speedup vs baseline: 1.5263x; 1.4368x over previous
//
#include <hip/hip_runtime.h>
#include <hip/hip_bf16.h>
#include <cstdio>
#include <cstdint>

typedef __bf16 bf16x8 __attribute__((ext_vector_type(8)));
typedef unsigned short u16;
typedef u16 u16x8 __attribute__((ext_vector_type(8)));
typedef float f32x4 __attribute__((ext_vector_type(4)));

#define DEV __device__ __forceinline__

static constexpr int B_ = 8, S_ = 2048, E_ = 768, NQ_ = 128, FF_ = 3072;
static constexpr int BS_ = B_ * S_;

DEV u16 f2b(float f) {
    unsigned u = __builtin_bit_cast(unsigned, f);
    unsigned r = (u + 0x7fffu + ((u >> 16) & 1u)) >> 16;
    return (u16)r;
}

#define GLD16(gp, lp) __builtin_amdgcn_global_load_lds( \
    (const __attribute__((address_space(1))) void*)(gp), \
    (__attribute__((address_space(3))) void*)(lp), 16, 0, 0)

// ---------------------------------------------------------------------------
// f32 -> bf16 convert (vectorized float4 -> ushort4)
// ---------------------------------------------------------------------------
__global__ void cvt_bf16(const float* __restrict__ in, u16* __restrict__ out, int n)
{
    const int stride = gridDim.x * blockDim.x * 4;
    for (int i = (blockIdx.x * blockDim.x + threadIdx.x) * 4; i < n; i += stride) {
        const float4 f = *(const float4*)(in + i);
        ushort4 u;
        u.x = f2b(f.x); u.y = f2b(f.y); u.z = f2b(f.z); u.w = f2b(f.w);
        *(ushort4*)(out + i) = u;
    }
}

// ---------------------------------------------------------------------------
// K-step helpers for the 256x256 GEMM.
//
// Accumulator lives in AGPRs via inline-asm MFMA ("a" constraints): rounds
// 2-6 showed the compiler leaving the 128-float accumulator in scratch
// (VGPR_Count 52 vs 128-float acc; deep-K GEMMs wrote 0.9-1.25 GB vs
// <=134 MB unique output = spill writebacks; spill reads hit L2, hence
// WRITE >> FETCH excess).  Round 7's plain "+a" port failed numerically
// from the two boundary hazards raw asm exposes, fixed here:
//   (1) no accvgpr_write init: first K-step uses src-C = inline constant 0
//       ("=a" output), so no VALU-write -> MFMA-read-C hazard exists;
//   (2) epilogue accvgpr reads: sched_barrier + 2x s_nop 7 after the K-loop
//       (16 cyc >= the 4-pass 16x16x32 MFMA -> VALU-read wait; sched_barrier
//       keeps hipcc from hoisting the reads across the nops).
// MFMA->MFMA same-accumulator chains are HW-interlocked (no nops needed).
// ---------------------------------------------------------------------------
template<int K>
DEV void kstage(const u16* A, const u16* Bm, u16* As, u16* Bs,
                int m0, int n0, int k0, int w, int t)
{
    #pragma unroll
    for (int r = 0; r < 4; ++r) {
        const int ci = r * 512 + t;
        const int row = ci >> 3;                       // 0..255
        const int colb = ((ci & 7) * 16) ^ ((row & 7) << 4);
        GLD16(A  + (size_t)(m0 + row) * K + k0 + (colb >> 1),
              As + (size_t)(r * 512 + w * 64) * 8);
        GLD16(Bm + (size_t)(n0 + row) * K + k0 + (colb >> 1),
              Bs + (size_t)(r * 512 + w * 64) * 8);
    }
}

template<bool FIRST>
DEV void kcompute(const u16* As, const u16* Bs, f32x4 (&acc)[8][4],
                  int wr, int wc, int lane)
{
    #pragma unroll
    for (int kk = 0; kk < 2; ++kk) {
        bf16x8 af[8], bf[4];
        const int cb = kk * 64 + ((lane >> 4) << 4);   // byte offset in row
        #pragma unroll
        for (int m = 0; m < 8; ++m) {
            const int row = wr * 128 + m * 16 + (lane & 15);
            af[m] = *(const bf16x8*)((const char*)As + row * 128 + (cb ^ ((row & 7) << 4)));
        }
        #pragma unroll
        for (int n = 0; n < 4; ++n) {
            const int row = wc * 64 + n * 16 + (lane & 15);
            bf[n] = *(const bf16x8*)((const char*)Bs + row * 128 + (cb ^ ((row & 7) << 4)));
        }
        #pragma unroll
        for (int m = 0; m < 8; ++m)
            #pragma unroll
            for (int n = 0; n < 4; ++n) {
                if (FIRST && kk == 0)
                    asm("v_mfma_f32_16x16x32_bf16 %0, %1, %2, 0"
                        : "=a"(acc[m][n]) : "v"(af[m]), "v"(bf[n]));
                else
                    asm("v_mfma_f32_16x16x32_bf16 %0, %1, %2, %0"
                        : "+a"(acc[m][n]) : "v"(af[m]), "v"(bf[n]));
            }
    }
}

// ---------------------------------------------------------------------------
// Templated (optionally batched) GEMM: C[M,N] = A[M,K] * B[N,K]^T
// 256x256 tile, BK=64, 8 waves (2x4 of 128x64), 512 threads,
// global_load_lds staging with XOR-swizzled LDS (inverse swizzle applied to
// the global source address).  Accumulator in AGPRs (see kcompute).
//
// blockIdx.z = batch; sA/sB/sC are per-batch element strides (0 if unbatched).
// MODE 0: out bf16 = cos(c + bias[col])       (qa)
// MODE 1: out bf16 = relu(c + bias[col])      (h)
// MODE 2: out f32  = c + bias[col]            (ffn)
// MODE 3: out f32  = c                        (attn @ qa)
// MODE 4: out f32  = c * (1/sqrt(8))          (scores -- f32! logits need
//                                              more than bf16 precision)
// ---------------------------------------------------------------------------
template<int K, int MODE>
__global__ __launch_bounds__(512, 2)
void gemm_bt(const u16* __restrict__ A, const u16* __restrict__ Bm,
             const float* __restrict__ bias, void* __restrict__ out, int N,
             size_t sA, size_t sB, size_t sC)
{
    __shared__ u16 As[256 * 64];   // 32 KiB
    __shared__ u16 Bs[256 * 64];   // 32 KiB
    const int t = threadIdx.x;
    const int w = t >> 6, lane = t & 63;
    const int m0 = blockIdx.x * 256, n0 = blockIdx.y * 256;
    const int wr = w >> 2, wc = w & 3;      // 2 x 4 waves; wave tile 128x64
    A  += (size_t)blockIdx.z * sA;
    Bm += (size_t)blockIdx.z * sB;
    u16*   ob16 = (u16*)out   + (size_t)blockIdx.z * sC;
    float* of32 = (float*)out + (size_t)blockIdx.z * sC;
    f32x4 acc[8][4];               // written first by the C=0 MFMA form

    // peeled first K-step (C = 0, no accumulator init)
    kstage<K>(A, Bm, As, Bs, m0, n0, 0, w, t);
    __syncthreads();               // (compiler drains vmcnt before barrier)
    kcompute<true>(As, Bs, acc, wr, wc, lane);
    for (int k0 = 64; k0 < K; k0 += 64) {
        __syncthreads();           // prev compute's LDS reads done
        kstage<K>(A, Bm, As, Bs, m0, n0, k0, w, t);
        __syncthreads();           // staged tile ready
        kcompute<false>(As, Bs, acc, wr, wc, lane);
    }

    // hazard fence: MFMA(write acc) -> VALU/accvgpr_read in epilogue
    __builtin_amdgcn_sched_barrier(0);
    asm volatile("s_nop 7\n\ts_nop 7");
    __builtin_amdgcn_sched_barrier(0);

    // epilogue: C/D layout col = lane&15, row = (lane>>4)*4 + r
    #pragma unroll
    for (int m = 0; m < 8; ++m) {
        const int rowb = m0 + wr * 128 + m * 16 + ((lane >> 4) << 2);
        #pragma unroll
        for (int n = 0; n < 4; ++n) {
            const int col = n0 + wc * 64 + n * 16 + (lane & 15);
            float bv = 0.f;
            if (MODE == 0 || MODE == 1 || MODE == 2) bv = bias[col];
            #pragma unroll
            for (int r = 0; r < 4; ++r) {
                const float c = acc[m][n][r];
                const size_t idx = (size_t)(rowb + r) * N + col;
                if (MODE == 0)      ob16[idx] = f2b(cosf(c + bv));
                else if (MODE == 1) ob16[idx] = f2b(fmaxf(c + bv, 0.f));
                else if (MODE == 2) of32[idx] = c + bv;
                else if (MODE == 3) of32[idx] = c;
                else                of32[idx] = c * 0.35355339059327373f;
            }
        }
    }
}

// ---------------------------------------------------------------------------
// Tiled bf16 transpose: in [B][S][E] -> out [B][E][S], 64x64 tiles.
// ---------------------------------------------------------------------------
__global__ __launch_bounds__(256)
void transpose_bf16(const u16* __restrict__ in, u16* __restrict__ outp)
{
    __shared__ u16 tile[64][72];
    const int b = blockIdx.z;
    const int s0 = blockIdx.x * 64, d0 = blockIdx.y * 64;
    const int t = threadIdx.x;
    const u16* src = in + ((size_t)b * S_ + s0) * E_ + d0;
    #pragma unroll
    for (int i = 0; i < 2; ++i) {
        const int r = (t >> 3) + i * 32;
        const int c = (t & 7) * 8;
        u16x8 v = *(const u16x8*)(src + (size_t)r * E_ + c);
        #pragma unroll
        for (int e = 0; e < 8; ++e) tile[r][c + e] = v[e];
    }
    __syncthreads();
    u16* dst = outp + ((size_t)b * E_ + d0) * S_ + s0;
    #pragma unroll
    for (int i = 0; i < 2; ++i) {
        const int r = (t >> 3) + i * 32;   // d-row within tile
        const int c = (t & 7) * 8;         // s-col
        u16x8 v;
        #pragma unroll
        for (int e = 0; e < 8; ++e) v[e] = tile[c + e][r];
        *(u16x8*)(dst + (size_t)r * S_ + c) = v;
    }
}

// ---------------------------------------------------------------------------
// Row softmax: read 2048 f32 logits, write 2048 bf16 probabilities.
// One block per row, 256 threads x 8 elements.
// ---------------------------------------------------------------------------
__global__ __launch_bounds__(256)
void softmax_rows(const float* __restrict__ s, u16* __restrict__ pout)
{
    const int t = threadIdx.x;
    const float* row = s + (size_t)blockIdx.x * (size_t)S_;
    float f[8];
    {
        const float4 a = *(const float4*)(row + t * 8);
        const float4 b = *(const float4*)(row + t * 8 + 4);
        f[0] = a.x; f[1] = a.y; f[2] = a.z; f[3] = a.w;
        f[4] = b.x; f[5] = b.y; f[6] = b.z; f[7] = b.w;
    }
    float mx = f[0];
    #pragma unroll
    for (int e = 1; e < 8; ++e) mx = fmaxf(mx, f[e]);
    #pragma unroll
    for (int d = 1; d < 64; d <<= 1) mx = fmaxf(mx, __shfl_xor(mx, d));
    __shared__ float sh[8];
    if ((t & 63) == 0) sh[t >> 6] = mx;
    __syncthreads();
    mx = fmaxf(fmaxf(sh[0], sh[1]), fmaxf(sh[2], sh[3]));
    float sum = 0.f;
    #pragma unroll
    for (int e = 0; e < 8; ++e) { f[e] = __expf(f[e] - mx); sum += f[e]; }
    #pragma unroll
    for (int d = 1; d < 64; d <<= 1) sum += __shfl_xor(sum, d);
    if ((t & 63) == 0) sh[4 + (t >> 6)] = sum;
    __syncthreads();
    sum = sh[4] + sh[5] + sh[6] + sh[7];
    const float inv = 1.f / sum;
    u16x8 v;
    #pragma unroll
    for (int e = 0; e < 8; ++e) v[e] = f2b(f[e] * inv);
    *(u16x8*)(pout + (size_t)blockIdx.x * (size_t)S_ + t * 8) = v;
}

// ---------------------------------------------------------------------------
// Fused residual + LayerNorm (+ optional qf = cos(y[:128] + theta) epilogue).
// One block per row (768 cols, 256 threads x 3).
// ---------------------------------------------------------------------------
__global__ __launch_bounds__(256)
void ln_fuse(const float* __restrict__ a, const float* __restrict__ res,
             const float* __restrict__ g, const float* __restrict__ bb,
             const float* __restrict__ theta, float* __restrict__ out,
             u16* __restrict__ qf)
{
    const int row = blockIdx.x, t = threadIdx.x;
    const float* ar = a + (size_t)row * E_;
    const float* rr = res + (size_t)row * E_;
    float v0 = ar[t] + rr[t];
    float v1 = ar[t + 256] + rr[t + 256];
    float v2 = ar[t + 512] + rr[t + 512];
    float s1 = v0 + v1 + v2;
    float s2 = v0 * v0 + v1 * v1 + v2 * v2;
    #pragma unroll
    for (int d = 1; d < 64; d <<= 1) { s1 += __shfl_xor(s1, d); s2 += __shfl_xor(s2, d); }
    __shared__ float sh[8];
    if ((t & 63) == 0) { sh[t >> 6] = s1; sh[4 + (t >> 6)] = s2; }
    __syncthreads();
    s1 = sh[0] + sh[1] + sh[2] + sh[3];
    s2 = sh[4] + sh[5] + sh[6] + sh[7];
    const float mean = s1 * (1.f / 768.f);
    const float var = s2 * (1.f / 768.f) - mean * mean;
    const float rs = rsqrtf(var + 1e-5f);
    float* orow = out + (size_t)row * E_;
    const float y0 = (v0 - mean) * rs * g[t] + bb[t];
    const float y1 = (v1 - mean) * rs * g[t + 256] + bb[t + 256];
    const float y2 = (v2 - mean) * rs * g[t + 512] + bb[t + 512];
    orow[t] = y0; orow[t + 256] = y1; orow[t + 512] = y2;
    if (qf != nullptr && t < NQ_)
        qf[(size_t)row * NQ_ + t] = f2b(cosf(y0 + theta[t]));
}

// ---------------------------------------------------------------------------
// Workspace arena plan (216 MiB arena + 5.25 MiB fixed tail).
// Timeline:  t0 cvt | t1 gemm0 | t2 transpose | t3 scores | t4 softmax
//            t5 PV  | t6 ln1   | t7 ffn1      | t8 ffn2   | t9 ln2
// buffer   offset(MiB) size  live
//  x_b        0       24    t0-t1
//  Wp_b      24       1.13  t0-t1
//  qa       128       24    t1-t3
//  qaT      192       24    t2-t5
//  scores     0      128    t3-t4
//  probs    128       64    t4-t5
//  ao         0       48    t5-t6,t8-t9
//  x1       144       48    t6-t9
//  qf       192        4    t6-t7
//  h         48       96    t7-t8
// ---------------------------------------------------------------------------
extern "C" void kernel_launch(void* const* d_in, const int* in_sizes, int n_in,
                              void* d_out, int out_size, void* d_ws, size_t ws_size,
                              hipStream_t stream)
{
    (void)in_sizes; (void)n_in; (void)out_size;
    const float* x    = (const float*)d_in[0];
    const float* Wp   = (const float*)d_in[1];
    const float* trx  = (const float*)d_in[2];
    const float* try_ = (const float*)d_in[3];
    const float* W1   = (const float*)d_in[4];
    const float* b1   = (const float*)d_in[5];
    const float* W2   = (const float*)d_in[6];
    const float* b2   = (const float*)d_in[7];
    const float* g1   = (const float*)d_in[8];
    const float* bb1  = (const float*)d_in[9];
    const float* g2   = (const float*)d_in[10];
    const float* bb2  = (const float*)d_in[11];
    float* out = (float*)d_out;

    const size_t MiB = (size_t)1 << 20;
    char* arena = (char*)d_ws;
    u16*   x_b    = (u16*)  (arena + 0);
    u16*   Wp_b   = (u16*)  (arena + 24 * MiB);
    u16*   qa     = (u16*)  (arena + 128 * MiB);
    u16*   qaT    = (u16*)  (arena + 192 * MiB);
    float* scores = (float*)(arena + 0);
    u16*   probs  = (u16*)  (arena + 128 * MiB);
    float* ao     = (float*)(arena + 0);
    float* x1     = (float*)(arena + 144 * MiB);
    u16*   qf     = (u16*)  (arena + 192 * MiB);
    u16*   h      = (u16*)  (arena + 48 * MiB);
    u16*   W1_b   = (u16*)  (arena + 216 * MiB);
    u16*   W2_b   = (u16*)  (arena + 216 * MiB + (size_t)FF_ * NQ_ * 2);
    const size_t need = 216 * MiB + (size_t)FF_ * NQ_ * 2 + (size_t)E_ * FF_ * 2;
    if (need > ws_size) {
        fprintf(stderr, "kernel_launch: ws too small: need=%zu have=%zu\n", need, ws_size);
        return;
    }

    cvt_bf16<<<512, 256, 0, stream>>>(x,  x_b,  BS_ * E_);
    cvt_bf16<<<64,  256, 0, stream>>>(Wp, Wp_b, E_ * E_);
    cvt_bf16<<<64,  256, 0, stream>>>(W1, W1_b, FF_ * NQ_);
    cvt_bf16<<<64,  256, 0, stream>>>(W2, W2_b, E_ * FF_);

    // qa = cos(x @ Wp^T + theta_rx)
    gemm_bt<E_, 0><<<dim3(BS_ / 256, E_ / 256), 512, 0, stream>>>(
        x_b, Wp_b, trx, qa, E_, 0, 0, 0);
    // qaT[b][d][s] = qa[b][s][d]
    transpose_bf16<<<dim3(S_ / 64, E_ / 64, B_), 256, 0, stream>>>(qa, qaT);
    // scores = (qa @ qa^T) / sqrt(8), f32, per batch
    gemm_bt<E_, 4><<<dim3(S_ / 256, S_ / 256, B_), 512, 0, stream>>>(
        qa, qa, nullptr, scores, S_,
        (size_t)S_ * E_, (size_t)S_ * E_, (size_t)S_ * S_);
    // probs = softmax(scores) in bf16
    softmax_rows<<<BS_, 256, 0, stream>>>(scores, probs);
    // ao = probs @ qa  (= probs [S,S] * qaT [E,S]^T), f32, per batch
    gemm_bt<S_, 3><<<dim3(S_ / 256, E_ / 256, B_), 512, 0, stream>>>(
        probs, qaT, nullptr, ao, E_,
        (size_t)S_ * S_, (size_t)E_ * S_, (size_t)S_ * E_);

    ln_fuse<<<BS_, 256, 0, stream>>>(ao, x, g1, bb1, try_, x1, qf);
    gemm_bt<NQ_, 1><<<dim3(BS_ / 256, FF_ / 256), 512, 0, stream>>>(
        qf, W1_b, b1, h, FF_, 0, 0, 0);
    gemm_bt<FF_, 2><<<dim3(BS_ / 256, E_ / 256), 512, 0, stream>>>(
        h, W2_b, b2, ao, E_, 0, 0, 0);
    ln_fuse<<<BS_, 256, 0, stream>>>(ao, x1, g2, bb2, nullptr, out, nullptr);
}

// Round 10
// 415.051 us; speedup vs baseline: 2.2583x; 1.4796x over previous
//
#include <hip/hip_runtime.h>
#include <hip/hip_bf16.h>
#include <cstdio>
#include <cstdint>

typedef __bf16 bf16x8 __attribute__((ext_vector_type(8)));
typedef unsigned short u16;
typedef u16 u16x8 __attribute__((ext_vector_type(8)));
typedef float f32x4 __attribute__((ext_vector_type(4)));

#define DEV __device__ __forceinline__

static constexpr int B_ = 8, S_ = 2048, E_ = 768, NQ_ = 128, FF_ = 3072;
static constexpr int BS_ = B_ * S_;

DEV u16 f2b(float f) {
    unsigned u = __builtin_bit_cast(unsigned, f);
    unsigned r = (u + 0x7fffu + ((u >> 16) & 1u)) >> 16;
    return (u16)r;
}

#define GLD16(gp, lp) __builtin_amdgcn_global_load_lds( \
    (const __attribute__((address_space(1))) void*)(gp), \
    (__attribute__((address_space(3))) void*)(lp), 16, 0, 0)

// ---------------------------------------------------------------------------
// f32 -> bf16 convert (vectorized float4 -> ushort4)
// ---------------------------------------------------------------------------
__global__ void cvt_bf16(const float* __restrict__ in, u16* __restrict__ out, int n)
{
    const int stride = gridDim.x * blockDim.x * 4;
    for (int i = (blockIdx.x * blockDim.x + threadIdx.x) * 4; i < n; i += stride) {
        const float4 f = *(const float4*)(in + i);
        ushort4 u;
        u.x = f2b(f.x); u.y = f2b(f.y); u.z = f2b(f.z); u.w = f2b(f.w);
        *(ushort4*)(out + i) = u;
    }
}

// ---------------------------------------------------------------------------
// K-step helpers for the 256x256 GEMM.
//
// Accumulator in AGPRs via inline-asm MFMA ("a" constraints): the compiler
// refused to promote the 128-float acc (scratch spill = 0.9-1.25 GB writes
// per deep-K dispatch, rounds 2-6).  Hazard discipline (round 7 -> 8):
//   (1) first K-step uses src-C = inline 0 ("=a"), no accvgpr_write init;
//   (2) sched_barrier + 2x s_nop 7 before the epilogue's accvgpr reads.
// MFMA->MFMA same-accumulator chains are HW-interlocked.
// ---------------------------------------------------------------------------
template<int K>
DEV void kstage(const u16* A, const u16* Bm, u16* As, u16* Bs,
                int m0, int n0, int k0, int w, int t)
{
    #pragma unroll
    for (int r = 0; r < 4; ++r) {
        const int ci = r * 512 + t;
        const int row = ci >> 3;                       // 0..255
        const int colb = ((ci & 7) * 16) ^ ((row & 7) << 4);
        GLD16(A  + (size_t)(m0 + row) * K + k0 + (colb >> 1),
              As + (size_t)(r * 512 + w * 64) * 8);
        GLD16(Bm + (size_t)(n0 + row) * K + k0 + (colb >> 1),
              Bs + (size_t)(r * 512 + w * 64) * 8);
    }
}

template<bool FIRST>
DEV void kcompute(const u16* As, const u16* Bs, f32x4 (&acc)[8][4],
                  int wr, int wc, int lane)
{
    #pragma unroll
    for (int kk = 0; kk < 2; ++kk) {
        bf16x8 af[8], bf[4];
        const int cb = kk * 64 + ((lane >> 4) << 4);   // byte offset in row
        #pragma unroll
        for (int m = 0; m < 8; ++m) {
            const int row = wr * 128 + m * 16 + (lane & 15);
            af[m] = *(const bf16x8*)((const char*)As + row * 128 + (cb ^ ((row & 7) << 4)));
        }
        #pragma unroll
        for (int n = 0; n < 4; ++n) {
            const int row = wc * 64 + n * 16 + (lane & 15);
            bf[n] = *(const bf16x8*)((const char*)Bs + row * 128 + (cb ^ ((row & 7) << 4)));
        }
        #pragma unroll
        for (int m = 0; m < 8; ++m)
            #pragma unroll
            for (int n = 0; n < 4; ++n) {
                if (FIRST && kk == 0)
                    asm("v_mfma_f32_16x16x32_bf16 %0, %1, %2, 0"
                        : "=a"(acc[m][n]) : "v"(af[m]), "v"(bf[n]));
                else
                    asm("v_mfma_f32_16x16x32_bf16 %0, %1, %2, %0"
                        : "+a"(acc[m][n]) : "v"(af[m]), "v"(bf[n]));
            }
    }
}

// ---------------------------------------------------------------------------
// Templated (optionally batched) GEMM: C[M,N] = A[M,K] * B[N,K]^T
// 256x256 tile, BK=64, 8 waves (2x4 of 128x64), 512 threads.
// DOUBLE-BUFFERED LDS (128 KiB): stage tile k+1 before computing tile k,
// ONE __syncthreads per K-step (round 8: deep-K gemms were latency-bound at
// 850 GB/s / MfmaUtil 21% with the 2-barrier structure).  Buffer selection
// by offset arithmetic, NOT a pointer array (round 9: an LDS-pointer array
// initializer is an unsupported addrspacecast static init on gfx950).
// MODE 0 epilogue uses __cosf: libm cosf's register footprint in the
// 128-live-acc epilogue caused scratch spill (round 8: gemm0 wrote 614 MB
// vs 25 MB unique output; __cosf error ~1e-6 << bf16 rounding 2e-3).
//
// blockIdx.z = batch; sA/sB/sC are per-batch element strides (0 if unbatched).
// MODE 0: out bf16 = cos(c + bias[col])       (qa)
// MODE 1: out bf16 = relu(c + bias[col])      (h)
// MODE 2: out f32  = c + bias[col]            (ffn)
// MODE 3: out f32  = c                        (attn @ qa)
// MODE 4: out f32  = c * (1/sqrt(8))          (scores -- f32! logits need
//                                              more than bf16 precision)
// ---------------------------------------------------------------------------
template<int K, int MODE>
__global__ __launch_bounds__(512, 2)
void gemm_bt(const u16* __restrict__ A, const u16* __restrict__ Bm,
             const float* __restrict__ bias, void* __restrict__ out, int N,
             size_t sA, size_t sB, size_t sC)
{
    __shared__ u16 lds[4 * 256 * 64];      // 128 KiB: [buf0 A|B][buf1 A|B]
    const int t = threadIdx.x;
    const int w = t >> 6, lane = t & 63;
    const int m0 = blockIdx.x * 256, n0 = blockIdx.y * 256;
    const int wr = w >> 2, wc = w & 3;      // 2 x 4 waves; wave tile 128x64
    A  += (size_t)blockIdx.z * sA;
    Bm += (size_t)blockIdx.z * sB;
    u16*   ob16 = (u16*)out   + (size_t)blockIdx.z * sC;
    float* of32 = (float*)out + (size_t)blockIdx.z * sC;
    f32x4 acc[8][4];               // written first by the C=0 MFMA form

    // prologue: stage tile 0, then pipeline {stage k+1 || compute k}
    kstage<K>(A, Bm, lds, lds + 16384, m0, n0, 0, w, t);
    __syncthreads();                       // drains vmcnt: buf0 ready
    int cur = 0;
    for (int k0 = 0; k0 < K; k0 += 64) {
        const int nxt = cur ^ 32768;
        if (k0 + 64 < K)
            kstage<K>(A, Bm, lds + nxt, lds + nxt + 16384, m0, n0, k0 + 64, w, t);
        if (k0 == 0) kcompute<true >(lds + cur, lds + cur + 16384, acc, wr, wc, lane);
        else         kcompute<false>(lds + cur, lds + cur + 16384, acc, wr, wc, lane);
        __syncthreads();                   // drains vmcnt: next buf ready;
        cur = nxt;                         // all waves done reading cur
    }

    // hazard fence: MFMA(write acc) -> VALU/accvgpr_read in epilogue
    __builtin_amdgcn_sched_barrier(0);
    asm volatile("s_nop 7\n\ts_nop 7");
    __builtin_amdgcn_sched_barrier(0);

    // epilogue: C/D layout col = lane&15, row = (lane>>4)*4 + r
    #pragma unroll
    for (int m = 0; m < 8; ++m) {
        const int rowb = m0 + wr * 128 + m * 16 + ((lane >> 4) << 2);
        #pragma unroll
        for (int n = 0; n < 4; ++n) {
            const int col = n0 + wc * 64 + n * 16 + (lane & 15);
            float bv = 0.f;
            if (MODE == 0 || MODE == 1 || MODE == 2) bv = bias[col];
            #pragma unroll
            for (int r = 0; r < 4; ++r) {
                const float c = acc[m][n][r];
                const size_t idx = (size_t)(rowb + r) * N + col;
                if (MODE == 0)      ob16[idx] = f2b(__cosf(c + bv));
                else if (MODE == 1) ob16[idx] = f2b(fmaxf(c + bv, 0.f));
                else if (MODE == 2) of32[idx] = c + bv;
                else if (MODE == 3) of32[idx] = c;
                else                of32[idx] = c * 0.35355339059327373f;
            }
        }
    }
}

// ---------------------------------------------------------------------------
// Tiled bf16 transpose: in [B][S][E] -> out [B][E][S], 64x64 tiles.
// ---------------------------------------------------------------------------
__global__ __launch_bounds__(256)
void transpose_bf16(const u16* __restrict__ in, u16* __restrict__ outp)
{
    __shared__ u16 tile[64][72];
    const int b = blockIdx.z;
    const int s0 = blockIdx.x * 64, d0 = blockIdx.y * 64;
    const int t = threadIdx.x;
    const u16* src = in + ((size_t)b * S_ + s0) * E_ + d0;
    #pragma unroll
    for (int i = 0; i < 2; ++i) {
        const int r = (t >> 3) + i * 32;
        const int c = (t & 7) * 8;
        u16x8 v = *(const u16x8*)(src + (size_t)r * E_ + c);
        #pragma unroll
        for (int e = 0; e < 8; ++e) tile[r][c + e] = v[e];
    }
    __syncthreads();
    u16* dst = outp + ((size_t)b * E_ + d0) * S_ + s0;
    #pragma unroll
    for (int i = 0; i < 2; ++i) {
        const int r = (t >> 3) + i * 32;   // d-row within tile
        const int c = (t & 7) * 8;         // s-col
        u16x8 v;
        #pragma unroll
        for (int e = 0; e < 8; ++e) v[e] = tile[c + e][r];
        *(u16x8*)(dst + (size_t)r * S_ + c) = v;
    }
}

// ---------------------------------------------------------------------------
// Row softmax: read 2048 f32 logits, write 2048 bf16 probabilities.
// One block per row, 256 threads x 8 elements.
// ---------------------------------------------------------------------------
__global__ __launch_bounds__(256)
void softmax_rows(const float* __restrict__ s, u16* __restrict__ pout)
{
    const int t = threadIdx.x;
    const float* row = s + (size_t)blockIdx.x * (size_t)S_;
    float f[8];
    {
        const float4 a = *(const float4*)(row + t * 8);
        const float4 b = *(const float4*)(row + t * 8 + 4);
        f[0] = a.x; f[1] = a.y; f[2] = a.z; f[3] = a.w;
        f[4] = b.x; f[5] = b.y; f[6] = b.z; f[7] = b.w;
    }
    float mx = f[0];
    #pragma unroll
    for (int e = 1; e < 8; ++e) mx = fmaxf(mx, f[e]);
    #pragma unroll
    for (int d = 1; d < 64; d <<= 1) mx = fmaxf(mx, __shfl_xor(mx, d));
    __shared__ float sh[8];
    if ((t & 63) == 0) sh[t >> 6] = mx;
    __syncthreads();
    mx = fmaxf(fmaxf(sh[0], sh[1]), fmaxf(sh[2], sh[3]));
    float sum = 0.f;
    #pragma unroll
    for (int e = 0; e < 8; ++e) { f[e] = __expf(f[e] - mx); sum += f[e]; }
    #pragma unroll
    for (int d = 1; d < 64; d <<= 1) sum += __shfl_xor(sum, d);
    if ((t & 63) == 0) sh[4 + (t >> 6)] = sum;
    __syncthreads();
    sum = sh[4] + sh[5] + sh[6] + sh[7];
    const float inv = 1.f / sum;
    u16x8 v;
    #pragma unroll
    for (int e = 0; e < 8; ++e) v[e] = f2b(f[e] * inv);
    *(u16x8*)(pout + (size_t)blockIdx.x * (size_t)S_ + t * 8) = v;
}

// ---------------------------------------------------------------------------
// Fused residual + LayerNorm (+ optional qf = cos(y[:128] + theta) epilogue).
// One block per row (768 cols, 256 threads x 3).
// ---------------------------------------------------------------------------
__global__ __launch_bounds__(256)
void ln_fuse(const float* __restrict__ a, const float* __restrict__ res,
             const float* __restrict__ g, const float* __restrict__ bb,
             const float* __restrict__ theta, float* __restrict__ out,
             u16* __restrict__ qf)
{
    const int row = blockIdx.x, t = threadIdx.x;
    const float* ar = a + (size_t)row * E_;
    const float* rr = res + (size_t)row * E_;
    float v0 = ar[t] + rr[t];
    float v1 = ar[t + 256] + rr[t + 256];
    float v2 = ar[t + 512] + rr[t + 512];
    float s1 = v0 + v1 + v2;
    float s2 = v0 * v0 + v1 * v1 + v2 * v2;
    #pragma unroll
    for (int d = 1; d < 64; d <<= 1) { s1 += __shfl_xor(s1, d); s2 += __shfl_xor(s2, d); }
    __shared__ float sh[8];
    if ((t & 63) == 0) { sh[t >> 6] = s1; sh[4 + (t >> 6)] = s2; }
    __syncthreads();
    s1 = sh[0] + sh[1] + sh[2] + sh[3];
    s2 = sh[4] + sh[5] + sh[6] + sh[7];
    const float mean = s1 * (1.f / 768.f);
    const float var = s2 * (1.f / 768.f) - mean * mean;
    const float rs = rsqrtf(var + 1e-5f);
    float* orow = out + (size_t)row * E_;
    const float y0 = (v0 - mean) * rs * g[t] + bb[t];
    const float y1 = (v1 - mean) * rs * g[t + 256] + bb[t + 256];
    const float y2 = (v2 - mean) * rs * g[t + 512] + bb[t + 512];
    orow[t] = y0; orow[t + 256] = y1; orow[t + 512] = y2;
    if (qf != nullptr && t < NQ_)
        qf[(size_t)row * NQ_ + t] = f2b(cosf(y0 + theta[t]));
}

// ---------------------------------------------------------------------------
// Workspace arena plan (216 MiB arena + 5.25 MiB fixed tail).
// Timeline:  t0 cvt | t1 gemm0 | t2 transpose | t3 scores | t4 softmax
//            t5 PV  | t6 ln1   | t7 ffn1      | t8 ffn2   | t9 ln2
// buffer   offset(MiB) size  live
//  x_b        0       24    t0-t1
//  Wp_b      24       1.13  t0-t1
//  qa       128       24    t1-t3
//  qaT      192       24    t2-t5
//  scores     0      128    t3-t4
//  probs    128       64    t4-t5
//  ao         0       48    t5-t6,t8-t9
//  x1       144       48    t6-t9
//  qf       192        4    t6-t7
//  h         48       96    t7-t8
// ---------------------------------------------------------------------------
extern "C" void kernel_launch(void* const* d_in, const int* in_sizes, int n_in,
                              void* d_out, int out_size, void* d_ws, size_t ws_size,
                              hipStream_t stream)
{
    (void)in_sizes; (void)n_in; (void)out_size;
    const float* x    = (const float*)d_in[0];
    const float* Wp   = (const float*)d_in[1];
    const float* trx  = (const float*)d_in[2];
    const float* try_ = (const float*)d_in[3];
    const float* W1   = (const float*)d_in[4];
    const float* b1   = (const float*)d_in[5];
    const float* W2   = (const float*)d_in[6];
    const float* b2   = (const float*)d_in[7];
    const float* g1   = (const float*)d_in[8];
    const float* bb1  = (const float*)d_in[9];
    const float* g2   = (const float*)d_in[10];
    const float* bb2  = (const float*)d_in[11];
    float* out = (float*)d_out;

    const size_t MiB = (size_t)1 << 20;
    char* arena = (char*)d_ws;
    u16*   x_b    = (u16*)  (arena + 0);
    u16*   Wp_b   = (u16*)  (arena + 24 * MiB);
    u16*   qa     = (u16*)  (arena + 128 * MiB);
    u16*   qaT    = (u16*)  (arena + 192 * MiB);
    float* scores = (float*)(arena + 0);
    u16*   probs  = (u16*)  (arena + 128 * MiB);
    float* ao     = (float*)(arena + 0);
    float* x1     = (float*)(arena + 144 * MiB);
    u16*   qf     = (u16*)  (arena + 192 * MiB);
    u16*   h      = (u16*)  (arena + 48 * MiB);
    u16*   W1_b   = (u16*)  (arena + 216 * MiB);
    u16*   W2_b   = (u16*)  (arena + 216 * MiB + (size_t)FF_ * NQ_ * 2);
    const size_t need = 216 * MiB + (size_t)FF_ * NQ_ * 2 + (size_t)E_ * FF_ * 2;
    if (need > ws_size) {
        fprintf(stderr, "kernel_launch: ws too small: need=%zu have=%zu\n", need, ws_size);
        return;
    }

    cvt_bf16<<<512, 256, 0, stream>>>(x,  x_b,  BS_ * E_);
    cvt_bf16<<<64,  256, 0, stream>>>(Wp, Wp_b, E_ * E_);
    cvt_bf16<<<64,  256, 0, stream>>>(W1, W1_b, FF_ * NQ_);
    cvt_bf16<<<64,  256, 0, stream>>>(W2, W2_b, E_ * FF_);

    // qa = cos(x @ Wp^T + theta_rx)
    gemm_bt<E_, 0><<<dim3(BS_ / 256, E_ / 256), 512, 0, stream>>>(
        x_b, Wp_b, trx, qa, E_, 0, 0, 0);
    // qaT[b][d][s] = qa[b][s][d]
    transpose_bf16<<<dim3(S_ / 64, E_ / 64, B_), 256, 0, stream>>>(qa, qaT);
    // scores = (qa @ qa^T) / sqrt(8), f32, per batch
    gemm_bt<E_, 4><<<dim3(S_ / 256, S_ / 256, B_), 512, 0, stream>>>(
        qa, qa, nullptr, scores, S_,
        (size_t)S_ * E_, (size_t)S_ * E_, (size_t)S_ * S_);
    // probs = softmax(scores) in bf16
    softmax_rows<<<BS_, 256, 0, stream>>>(scores, probs);
    // ao = probs @ qa  (= probs [S,S] * qaT [E,S]^T), f32, per batch
    gemm_bt<S_, 3><<<dim3(S_ / 256, E_ / 256, B_), 512, 0, stream>>>(
        probs, qaT, nullptr, ao, E_,
        (size_t)S_ * S_, (size_t)E_ * S_, (size_t)S_ * E_);

    ln_fuse<<<BS_, 256, 0, stream>>>(ao, x, g1, bb1, try_, x1, qf);
    gemm_bt<NQ_, 1><<<dim3(BS_ / 256, FF_ / 256), 512, 0, stream>>>(
        qf, W1_b, b1, h, FF_, 0, 0, 0);
    gemm_bt<FF_, 2><<<dim3(BS_ / 256, E_ / 256), 512, 0, stream>>>(
        h, W2_b, b2, ao, E_, 0, 0, 0);
    ln_fuse<<<BS_, 256, 0, stream>>>(ao, x1, g2, bb2, nullptr, out, nullptr);
}